// Round 1
// 6219.868 us; speedup vs baseline: 2.1277x; 2.1277x over previous
//
#include <hip/hip_runtime.h>
#include <hip/hip_cooperative_groups.h>
#include <math.h>

namespace cg = cooperative_groups;

#define BB 64
#define TT 32
#define II 512
#define HH 1024
#define OO 512
#define NN 1024
#define MM 64
#define EPSF 1e-8f

// virtual concatenated weight-row space (all K=HH):
//   [0,70)    read head : Wk(64) Wb Wg Ws(3) Wga
//   [70,140)  write head: same
//   [140,204) We ; [204,268) Wa
//   [268,3340) Whh (3072)
//   [3340,3852) Who (512)
//   [3852,3904) zero pad
#define JGATES 268
#define JGH_END 3340
#define JOUT_END 3852
#define YSTR 3392          // Y row stride (only j<3340 stored)

struct P {
  const float *Wk_r,*bk_r,*Wb_r,*bb_r,*Wg_r,*bg_r,*Ws_r,*bs_r,*Wga_r,*bga_r;
  const float *Wk_w,*bk_w,*Wb_w,*bb_w,*Wg_w,*bg_w,*Ws_w,*bs_w,*Wga_w,*bga_w;
  const float *We,*be,*Wa,*ba,*W_r2i,*b_r2i,*Wih,*bih,*Whh,*bhh,*Who,*bho;
  const float *x, *mem0;
  float *outs, *wr, *ww, *memOut;          // output regions
  float *hA, *hB, *Y, *memT, *xi, *W_r2iT; // workspace
};

__device__ __forceinline__ float sigmf(float x){ return 1.f/(1.f+expf(-x)); }
__device__ __forceinline__ float splusf(float x){ return fmaxf(x,0.f) + log1pf(expf(-fabsf(x))); }
__device__ __forceinline__ float4 ld4(const float* p){ return *reinterpret_cast<const float4*>(p); }
__device__ __forceinline__ void st4(float* p, float4 v){ *reinterpret_cast<float4*>(p) = v; }
__device__ __forceinline__ float wredsum(float v){
  #pragma unroll
  for (int o = 32; o; o >>= 1) v += __shfl_xor(v, o);
  return v;
}
__device__ __forceinline__ float wredmax(float v){
  #pragma unroll
  for (int o = 32; o; o >>= 1) v = fmaxf(v, __shfl_xor(v, o));
  return v;
}

__device__ __forceinline__ const float* wrow_of(const P& p, int j) {
  if (j < 140) {
    const bool w = (j >= 70);
    int q = w ? j - 70 : j;
    if (q < 64)  return (w ? p.Wk_w  : p.Wk_r)  + (size_t)q * HH;
    if (q == 64) return  w ? p.Wb_w  : p.Wb_r;
    if (q == 65) return  w ? p.Wg_w  : p.Wg_r;
    if (q < 69)  return (w ? p.Ws_w  : p.Ws_r)  + (size_t)(q-66) * HH;
    return w ? p.Wga_w : p.Wga_r;
  }
  if (j < 204)      return p.We  + (size_t)(j-140)  * HH;
  if (j < JGATES)   return p.Wa  + (size_t)(j-204)  * HH;
  if (j < JGH_END)  return p.Whh + (size_t)(j-JGATES) * HH;
  if (j < JOUT_END) return p.Who + (size_t)(j-JGH_END) * HH;
  return nullptr;
}

__device__ __forceinline__ float bias_of(const P& p, int j) {
  if (j < 140) {
    const bool w = (j >= 70);
    int q = w ? j - 70 : j;
    if (q < 64)  return (w ? p.bk_w  : p.bk_r)[q];
    if (q == 64) return (w ? p.bb_w  : p.bb_r)[0];
    if (q == 65) return (w ? p.bg_w  : p.bg_r)[0];
    if (q < 69)  return (w ? p.bs_w  : p.bs_r)[q-66];
    return (w ? p.bga_w : p.bga_r)[0];
  }
  if (j < 204)      return p.be[j-140];
  if (j < JGATES)   return p.ba[j-204];
  if (j < JGH_END)  return p.bhh[j-JGATES];
  if (j < JOUT_END) return p.bho[j-JGH_END];
  return 0.f;
}

// ---------------- P1: fused matvec  Y[b][j] = W[j]·h[b] + bias ----------------
// tile: 16 b × 64 j, full K=1024. gates+gh rows -> Y ; out rows -> sigmoid -> outs[t-1]
__device__ void p1_phase(const P& p, float* smem, const float* hcur, int tstep, int jt, int bt) {
  float* hs = smem;            // [16][64]
  float* Ws = smem + 1024;     // [64][68]
  const int tid = threadIdx.x;
  const int b_l = tid >> 4, jq = tid & 15;   // compute mapping: 1 b x 4 j per thread
  const int jr  = tid >> 2, kq = tid & 3;    // staging mapping
  const int j0 = jt * 64, b0 = bt * 16;
  const float* wsrc = wrow_of(p, j0 + jr);
  const float* hrow = hcur + (size_t)(b0 + b_l) * HH;
  float4 acc = make_float4(0.f, 0.f, 0.f, 0.f);
  for (int kc = 0; kc < 16; ++kc) {
    const int k0 = kc * 64;
    float4 hv = ld4(hrow + k0 + 4*jq);
    float4 u[4];
    if (wsrc) {
      #pragma unroll
      for (int i = 0; i < 4; ++i) u[i] = ld4(wsrc + k0 + kq*16 + 4*i);
    } else {
      #pragma unroll
      for (int i = 0; i < 4; ++i) u[i] = make_float4(0.f,0.f,0.f,0.f);
    }
    __syncthreads();
    st4(&hs[b_l*64 + 4*jq], hv);
    const int kb = kq * 16;
    #pragma unroll
    for (int i = 0; i < 4; ++i) {
      Ws[(kb+4*i+0)*68 + jr] = u[i].x;
      Ws[(kb+4*i+1)*68 + jr] = u[i].y;
      Ws[(kb+4*i+2)*68 + jr] = u[i].z;
      Ws[(kb+4*i+3)*68 + jr] = u[i].w;
    }
    __syncthreads();
    #pragma unroll 16
    for (int kk = 0; kk < 64; ++kk) {
      float hb = hs[b_l*64 + kk];
      float4 wv = ld4(&Ws[kk*68 + 4*jq]);
      acc.x += hb*wv.x; acc.y += hb*wv.y; acc.z += hb*wv.z; acc.w += hb*wv.w;
    }
  }
  const int b = b0 + b_l;
  const int jbase = j0 + 4*jq;
  float vv[4] = {acc.x, acc.y, acc.z, acc.w};
  #pragma unroll
  for (int e = 0; e < 4; ++e) {
    int j = jbase + e;
    float v = vv[e] + bias_of(p, j);
    if (j < JGH_END) {
      p.Y[(size_t)b*YSTR + j] = v;
    } else if (j < JOUT_END) {
      if (tstep >= 1)
        p.outs[((size_t)b*TT + (tstep-1))*OO + (j - JGH_END)] = sigmf(v);
    }
  }
}

// ---------------- P2+P3: addressing (both heads) + read + erase/add + rinxi, one block per b ----------------
__device__ void p23_phase(const P& p, float* smem, int tstep, int b) {
  const int tid = threadIdx.x;
  const int wv = tid >> 6, lane = tid & 63;
  float* k_s  = smem;          // 64
  float* e_s  = smem + 64;     // 64
  float* a_s  = smem + 128;    // 64
  float* r_s  = smem + 192;    // 64
  float* scal = smem + 256;    // 8: beta,g,s0,s1,s2,gamma,knorm
  float* red  = smem + 264;    // 8
  float* wg_s = smem + 272;    // 1024
  float* wA   = smem + 1296;   // 1024 (new wr)
  float* wB   = smem + 2320;   // 1024 (new ww)
  const float* Yb = p.Y + (size_t)b*YSTR;
  float* mb = p.memT + (size_t)b*MM*NN;
  const int n4 = 4*tid;

  for (int head = 0; head < 2; ++head) {
    const int gb = head * 70;
    if (tid < 64) {
      float kv = tanhf(Yb[gb + tid]);
      k_s[tid] = kv;
      float q = wredsum(kv*kv);
      if (tid == 0) scal[6] = sqrtf(q);
    } else if (tid == 64) {
      scal[0] = splusf(Yb[gb+64]);         // beta
      scal[1] = sigmf(Yb[gb+65]);          // g
      float x0 = Yb[gb+66], x1 = Yb[gb+67], x2 = Yb[gb+68];
      float mx = fmaxf(x0, fmaxf(x1,x2));
      float e0 = expf(x0-mx), e1 = expf(x1-mx), e2 = expf(x2-mx);
      float inv = 1.f/(e0+e1+e2);
      scal[2] = e0*inv; scal[3] = e1*inv; scal[4] = e2*inv;
      scal[5] = 1.f + splusf(Yb[gb+69]);   // gamma
    }
    __syncthreads();
    const float beta = scal[0], g = scal[1];
    const float s0 = scal[2], s1 = scal[3], s2 = scal[4];
    const float gam = scal[5], kn = scal[6];
    // cosine similarity, lane-owns-n (4 n per thread), zero shuffles
    float4 sim = make_float4(0.f,0.f,0.f,0.f);
    float4 qq  = make_float4(0.f,0.f,0.f,0.f);
    #pragma unroll 4
    for (int m = 0; m < MM; ++m) {
      float km = k_s[m];
      float4 v = ld4(mb + m*NN + n4);
      sim.x += km*v.x; sim.y += km*v.y; sim.z += km*v.z; sim.w += km*v.w;
      qq.x  += v.x*v.x; qq.y += v.y*v.y; qq.z += v.z*v.z; qq.w += v.w*v.w;
    }
    float4 pp;
    pp.x = beta*sim.x/(kn*sqrtf(qq.x)+EPSF);
    pp.y = beta*sim.y/(kn*sqrtf(qq.y)+EPSF);
    pp.z = beta*sim.z/(kn*sqrtf(qq.z)+EPSF);
    pp.w = beta*sim.w/(kn*sqrtf(qq.w)+EPSF);
    // softmax over N=1024
    float mx = wredmax(fmaxf(fmaxf(pp.x,pp.y), fmaxf(pp.z,pp.w)));
    if (lane == 0) red[wv] = mx;
    __syncthreads();
    mx = fmaxf(fmaxf(red[0],red[1]), fmaxf(red[2],red[3]));
    pp.x = expf(pp.x-mx); pp.y = expf(pp.y-mx); pp.z = expf(pp.z-mx); pp.w = expf(pp.w-mx);
    float sm = wredsum(pp.x+pp.y+pp.z+pp.w);
    if (lane == 0) red[4+wv] = sm;
    __syncthreads();
    const float inv = 1.f/(red[4]+red[5]+red[6]+red[7]);
    float* wbuf = (head ? p.ww : p.wr) + (size_t)b*NN;
    float4 wp = ld4(wbuf + n4);
    float4 wg;
    wg.x = g*(pp.x*inv) + (1.f-g)*wp.x;
    wg.y = g*(pp.y*inv) + (1.f-g)*wp.y;
    wg.z = g*(pp.z*inv) + (1.f-g)*wp.z;
    wg.w = g*(pp.w*inv) + (1.f-g)*wp.w;
    st4(&wg_s[n4], wg);
    __syncthreads();
    // circular shift + sharpen
    float wm1 = wg_s[(n4 + NN - 1) & (NN-1)];
    float wp4 = wg_s[(n4 + 4) & (NN-1)];
    float4 wt;
    wt.x = s0*wm1  + s1*wg.x + s2*wg.y;
    wt.y = s0*wg.x + s1*wg.y + s2*wg.z;
    wt.z = s0*wg.y + s1*wg.z + s2*wg.w;
    wt.w = s0*wg.z + s1*wg.w + s2*wp4;
    float4 w;
    w.x = powf(wt.x + 1e-12f, gam);
    w.y = powf(wt.y + 1e-12f, gam);
    w.z = powf(wt.z + 1e-12f, gam);
    w.w = powf(wt.w + 1e-12f, gam);
    float ps = wredsum(w.x+w.y+w.z+w.w);
    if (lane == 0) red[wv] = ps;
    __syncthreads();
    const float invw = 1.f/((red[0]+red[1]+red[2]+red[3]) + EPSF);
    w.x *= invw; w.y *= invw; w.z *= invw; w.w *= invw;
    st4(wbuf + n4, w);
    float* wls = head ? wB : wA;
    st4(&wls[n4], w);
    __syncthreads();
  }
  // e, a
  if (tid < 64) {
    e_s[tid] = sigmf(Yb[140 + tid]);
    a_s[tid] = tanhf(Yb[204 + tid]);
  }
  __syncthreads();
  // r[m] = sum_n wr[n]*memT[m][n]   (old mem)
  for (int i = 0; i < 16; ++i) {
    const int m = (wv << 4) + i;
    const float* row = mb + m*NN;
    float acc = 0.f;
    #pragma unroll
    for (int c = 0; c < 4; ++c) {
      const int n = c*256 + lane*4;
      float4 v = ld4(row + n);
      float4 u = ld4(&wA[n]);
      acc += v.x*u.x + v.y*u.y + v.z*u.z + v.w*u.w;
    }
    acc = wredsum(acc);
    if (lane == 0) r_s[m] = acc;
  }
  __syncthreads();
  // erase/add (new ww), lane-owns-n
  {
    float4 w4 = ld4(&wB[n4]);
    for (int m = 0; m < MM; ++m) {
      const float em = e_s[m], am = a_s[m];
      float* rp = mb + m*NN + n4;
      float4 v = ld4(rp);
      v.x = v.x*(1.f - w4.x*em) + w4.x*am;
      v.y = v.y*(1.f - w4.y*em) + w4.y*am;
      v.z = v.z*(1.f - w4.z*em) + w4.z*am;
      v.w = v.w*(1.f - w4.w*em) + w4.w*am;
      st4(rp, v);
    }
  }
  // rinxi: xi = relu(x_t + relu(W_r2i r + b))
  #pragma unroll
  for (int rep = 0; rep < 2; ++rep) {
    const int ii = tid + rep*256;
    float acc = p.b_r2i[ii];
    #pragma unroll 4
    for (int m = 0; m < MM; ++m) acc += p.W_r2iT[m*II + ii] * r_s[m];
    float xv = p.x[((size_t)b*TT + tstep)*II + ii];
    p.xi[(size_t)b*II + ii] = fmaxf(xv + fmaxf(acc, 0.f), 0.f);
  }
}

// ---------------- P4+P5: gi = Wih·xi (triplet tiles, in registers) + GRU combine ----------------
__device__ void p45_phase(const P& p, float* smem, const float* hcur, float* hnew, int jt, int bt) {
  float* xs = smem;            // [16][64]
  float* W3 = smem + 1024;     // [64][196]
  const int tid = threadIdx.x;
  const int b_l = tid >> 4, jq = tid & 15;
  const int jr  = tid >> 2, kq = tid & 3;
  const int j0 = jt * 64, b0 = bt * 16;
  float4 a0 = ld4(p.bih +            j0 + 4*jq);
  float4 a1 = ld4(p.bih +   HH +     j0 + 4*jq);
  float4 a2 = ld4(p.bih + 2*HH +     j0 + 4*jq);
  const float* xrow = p.xi + (size_t)(b0 + b_l) * II;
  for (int kc = 0; kc < 8; ++kc) {
    const int k0 = kc * 64;
    float4 xv = ld4(xrow + k0 + 4*jq);
    float4 u[3][4];
    #pragma unroll
    for (int g2 = 0; g2 < 3; ++g2) {
      const float* rw = p.Wih + (size_t)(g2*HH + j0 + jr)*II + k0 + kq*16;
      #pragma unroll
      for (int i = 0; i < 4; ++i) u[g2][i] = ld4(rw + 4*i);
    }
    __syncthreads();
    st4(&xs[b_l*64 + 4*jq], xv);
    const int kb = kq * 16;
    #pragma unroll
    for (int g2 = 0; g2 < 3; ++g2) {
      #pragma unroll
      for (int i = 0; i < 4; ++i) {
        W3[(kb+4*i+0)*196 + 64*g2 + jr] = u[g2][i].x;
        W3[(kb+4*i+1)*196 + 64*g2 + jr] = u[g2][i].y;
        W3[(kb+4*i+2)*196 + 64*g2 + jr] = u[g2][i].z;
        W3[(kb+4*i+3)*196 + 64*g2 + jr] = u[g2][i].w;
      }
    }
    __syncthreads();
    #pragma unroll 8
    for (int kk = 0; kk < 64; ++kk) {
      float xb = xs[b_l*64 + kk];
      float4 w0 = ld4(&W3[kk*196 +        4*jq]);
      float4 w1 = ld4(&W3[kk*196 +  64 +  4*jq]);
      float4 w2 = ld4(&W3[kk*196 + 128 +  4*jq]);
      a0.x += xb*w0.x; a0.y += xb*w0.y; a0.z += xb*w0.z; a0.w += xb*w0.w;
      a1.x += xb*w1.x; a1.y += xb*w1.y; a1.z += xb*w1.z; a1.w += xb*w1.w;
      a2.x += xb*w2.x; a2.y += xb*w2.y; a2.z += xb*w2.z; a2.w += xb*w2.w;
    }
  }
  // GRU combine (gi in registers, gh from Y)
  const int b = b0 + b_l, j = j0 + 4*jq;
  const float* Yb = p.Y + (size_t)b*YSTR + JGATES;
  float4 ghr = ld4(Yb + j);
  float4 ghz = ld4(Yb + HH + j);
  float4 ghn = ld4(Yb + 2*HH + j);
  float4 hv  = ld4(hcur + (size_t)b*HH + j);
  float4 ho;
  {
    float r = sigmf(a0.x + ghr.x), z = sigmf(a1.x + ghz.x);
    float n = tanhf(a2.x + r*ghn.x); ho.x = (1.f-z)*n + z*hv.x;
  }
  {
    float r = sigmf(a0.y + ghr.y), z = sigmf(a1.y + ghz.y);
    float n = tanhf(a2.y + r*ghn.y); ho.y = (1.f-z)*n + z*hv.y;
  }
  {
    float r = sigmf(a0.z + ghr.z), z = sigmf(a1.z + ghz.z);
    float n = tanhf(a2.z + r*ghn.z); ho.z = (1.f-z)*n + z*hv.z;
  }
  {
    float r = sigmf(a0.w + ghr.w), z = sigmf(a1.w + ghz.w);
    float n = tanhf(a2.w + r*ghn.w); ho.w = (1.f-z)*n + z*hv.w;
  }
  st4(hnew + (size_t)b*HH + j, ho);
}

// ---------------- the single persistent cooperative kernel ----------------
__global__ __launch_bounds__(256, 1) void ntm_all(P p) {
  __shared__ float smem[13568];   // 54.3 KB, max over phases
  cg::grid_group grid = cg::this_grid();
  const int blk = blockIdx.x;
  const int tid = threadIdx.x;
  const int wv = tid >> 6, lane = tid & 63;

  // ---- prologue: pack W_r2i^T ; transpose mem0 -> memT[b][m][n] ----
  if (blk < 64) {
    const int m = blk;
    for (int ii = tid; ii < II; ii += 256)
      p.W_r2iT[m*II + ii] = p.W_r2i[(size_t)ii*MM + m];
  } else if (blk < 128) {
    const int b = blk - 64;
    float* tile = smem;  // [64][65]
    for (int nt = 0; nt < 16; ++nt) {
      const int n0 = nt * 64;
      #pragma unroll
      for (int i = 0; i < 16; ++i) {
        const int nn = (wv << 4) + i;
        tile[nn*65 + lane] = p.mem0[((size_t)b*NN + n0 + nn)*MM + lane];
      }
      __syncthreads();
      #pragma unroll
      for (int i = 0; i < 16; ++i) {
        const int m = (wv << 4) + i;
        p.memT[((size_t)b*MM + m)*NN + n0 + lane] = tile[lane*65 + m];
      }
      __syncthreads();
    }
  }
  grid.sync();

  // ---- time loop: 3 grid syncs per step ----
  for (int t = 0; t < TT; ++t) {
    const float* hcur = (t & 1) ? p.hB : p.hA;
    float* hnew = (t & 1) ? p.hA : p.hB;
    if (blk < 244) p1_phase(p, smem, hcur, t, blk >> 2, blk & 3);   // 61 j-tiles x 4 b-tiles
    grid.sync();
    if (blk < 64) p23_phase(p, smem, t, blk);
    grid.sync();
    if (blk < 64) p45_phase(p, smem, hcur, hnew, blk >> 2, blk & 3); // 16 j-tiles x 4 b-tiles
    grid.sync();
  }

  // ---- epilogue: out[T-1] from final h ; transpose memT -> memOut ----
  if (blk < 36) {
    p1_phase(p, smem, p.hA, TT, 52 + (blk >> 2), blk & 3);  // tiles 52..60 cover out rows
  } else if (blk < 100) {
    const int b = blk - 36;
    float* tile = smem;
    for (int nt = 0; nt < 16; ++nt) {
      const int n0 = nt * 64;
      #pragma unroll
      for (int i = 0; i < 16; ++i) {
        const int m = (wv << 4) + i;
        tile[lane*65 + m] = p.memT[((size_t)b*MM + m)*NN + n0 + lane];
      }
      __syncthreads();
      #pragma unroll
      for (int i = 0; i < 16; ++i) {
        const int nn = (wv << 4) + i;
        p.memOut[((size_t)b*NN + n0 + nn)*MM + lane] = tile[nn*65 + lane];
      }
      __syncthreads();
    }
  }
}

extern "C" void kernel_launch(void* const* d_in, const int* in_sizes, int n_in,
                              void* d_out, int out_size, void* d_ws, size_t ws_size,
                              hipStream_t stream) {
  const float* x    = (const float*)d_in[0];
  const float* h0   = (const float*)d_in[1];
  const float* wr0  = (const float*)d_in[2];
  const float* ww0  = (const float*)d_in[3];
  const float* mem0 = (const float*)d_in[4];
  P p;
  int i = 5;
  p.Wk_r  = (const float*)d_in[i++]; p.bk_r  = (const float*)d_in[i++];
  p.Wb_r  = (const float*)d_in[i++]; p.bb_r  = (const float*)d_in[i++];
  p.Wg_r  = (const float*)d_in[i++]; p.bg_r  = (const float*)d_in[i++];
  p.Ws_r  = (const float*)d_in[i++]; p.bs_r  = (const float*)d_in[i++];
  p.Wga_r = (const float*)d_in[i++]; p.bga_r = (const float*)d_in[i++];
  p.Wk_w  = (const float*)d_in[i++]; p.bk_w  = (const float*)d_in[i++];
  p.Wb_w  = (const float*)d_in[i++]; p.bb_w  = (const float*)d_in[i++];
  p.Wg_w  = (const float*)d_in[i++]; p.bg_w  = (const float*)d_in[i++];
  p.Ws_w  = (const float*)d_in[i++]; p.bs_w  = (const float*)d_in[i++];
  p.Wga_w = (const float*)d_in[i++]; p.bga_w = (const float*)d_in[i++];
  p.We    = (const float*)d_in[i++]; p.be    = (const float*)d_in[i++];
  p.Wa    = (const float*)d_in[i++]; p.ba    = (const float*)d_in[i++];
  p.W_r2i = (const float*)d_in[i++]; p.b_r2i = (const float*)d_in[i++];
  p.Wih   = (const float*)d_in[i++]; p.bih   = (const float*)d_in[i++];
  p.Whh   = (const float*)d_in[i++]; p.bhh   = (const float*)d_in[i++];
  p.Who   = (const float*)d_in[i++]; p.bho   = (const float*)d_in[i++];
  p.x = x; p.mem0 = mem0;

  float* out = (float*)d_out;
  p.outs   = out;                                  // (B,T,O)
  float* hOut = out + (size_t)BB*TT*OO;            // (B,H) final h
  p.hA     = hOut;
  p.wr     = hOut + (size_t)BB*HH;                 // (B,N)
  p.ww     = p.wr + (size_t)BB*NN;                 // (B,N)
  p.memOut = p.ww + (size_t)BB*NN;                 // (B,N,M)

  float* ws = (float*)d_ws;
  p.hB     = ws;  ws += (size_t)BB*HH;             // 64K
  p.Y      = ws;  ws += (size_t)BB*YSTR;           // 217K
  p.memT   = ws;  ws += (size_t)BB*MM*NN;          // 4.19M
  p.xi     = ws;  ws += (size_t)BB*II;             // 32K
  p.W_r2iT = ws;  ws += (size_t)MM*II;             // 32K   (total ~17.4 MB)

  hipMemcpyAsync(p.hA, h0,  (size_t)BB*HH*sizeof(float), hipMemcpyDeviceToDevice, stream);
  hipMemcpyAsync(p.wr, wr0, (size_t)BB*NN*sizeof(float), hipMemcpyDeviceToDevice, stream);
  hipMemcpyAsync(p.ww, ww0, (size_t)BB*NN*sizeof(float), hipMemcpyDeviceToDevice, stream);

  void* args[] = { (void*)&p };
  hipLaunchCooperativeKernel((const void*)ntm_all, dim3(256), dim3(256), args, 0, stream);
}